// Round 7
// baseline (285.117 us; speedup 1.0000x reference)
//
#include <hip/hip_runtime.h>
#include <hip/hip_bf16.h>
#include <stdint.h>

// EncoderLayer: B=8 N=1024 D=512 H=8 Dh=64 FF=2048
#define B_   8
#define N_   1024
#define DM   512
#define H_   8
#define DFF  2048
#define ROWS (B_ * N_)          // 8192
#define QKV_LD (3 * DM)         // 1536
#define LOG2E 1.4426950408889634f
#define SCL  (0.125f * LOG2E)   // att scale 1/8 folded into exp2

typedef __bf16 bf16x8 __attribute__((ext_vector_type(8)));
typedef float  f32x4  __attribute__((ext_vector_type(4)));

__device__ __forceinline__ void gld_lds16(const void* g, void* l) {
  __builtin_amdgcn_global_load_lds((__attribute__((address_space(1))) void*)g,
                                   (__attribute__((address_space(3))) void*)l, 16, 0, 0);
}

__device__ __forceinline__ unsigned short bfb(float x) {
  __bf16 h = (__bf16)x;
  unsigned short u;
  __builtin_memcpy(&u, &h, 2);
  return u;
}

// ------- fused: prep (x_q=q+pos etc -> bf16) + all weight transposes --------
__global__ __launch_bounds__(256) void prep_and_wt(
    const float* __restrict__ q, const float* __restrict__ k,
    const float* __restrict__ v, const float* __restrict__ pos,
    __bf16* __restrict__ xq, __bf16* __restrict__ xk, __bf16* __restrict__ xv,
    const float* __restrict__ Wq, const float* __restrict__ Wk,
    const float* __restrict__ Wv, const float* __restrict__ Wo,
    const float* __restrict__ W1, const float* __restrict__ W2,
    __bf16* __restrict__ WqkvT, __bf16* __restrict__ WoT,
    __bf16* __restrict__ W1T, __bf16* __restrict__ W2T) {
  __shared__ float tl[32][33];
  if (blockIdx.x < 4096) {                    // ---- prep part
    int i = blockIdx.x * 256 + threadIdx.x;   // float4 group
    float4 pv = ((const float4*)pos)[i];
    float4 qv = ((const float4*)q)[i];
    float4 kv = ((const float4*)k)[i];
    float4 vv = ((const float4*)v)[i];
    ushort4 o;
    o.x = bfb(qv.x + pv.x); o.y = bfb(qv.y + pv.y); o.z = bfb(qv.z + pv.z); o.w = bfb(qv.w + pv.w);
    ((ushort4*)xq)[i] = o;
    o.x = bfb(kv.x + pv.x); o.y = bfb(kv.y + pv.y); o.z = bfb(kv.z + pv.z); o.w = bfb(kv.w + pv.w);
    ((ushort4*)xk)[i] = o;
    o.x = bfb(vv.x); o.y = bfb(vv.y); o.z = bfb(vv.z); o.w = bfb(vv.w);
    ((ushort4*)xv)[i] = o;
    return;
  }
  int idx = blockIdx.x - 4096;                // ---- weight transpose part
  const float* src; __bf16* dst; int K, N, t;
  if (idx < 768) {
    src = idx < 256 ? Wq : (idx < 512 ? Wk : Wv);
    dst = WqkvT + (size_t)(idx >> 8) * 512 * 512;
    K = 512; N = 512; t = idx & 255;
  } else if (idx < 1024) { src = Wo; dst = WoT;  K = 512;  N = 512;  t = idx - 768; }
  else if (idx < 2048)   { src = W1; dst = W1T;  K = 512;  N = 2048; t = idx - 1024; }
  else                   { src = W2; dst = W2T;  K = 2048; N = 512;  t = idx - 2048; }
  int tiles_n = N >> 5;
  int tn = t & (tiles_n - 1), tk = t / tiles_n;
  int n0 = tn * 32, k0 = tk * 32;
  int x = threadIdx.x & 31, y4 = threadIdx.x >> 5;
  #pragma unroll
  for (int j = y4; j < 32; j += 8) tl[j][x] = src[(size_t)(k0 + j) * N + n0 + x];
  __syncthreads();
  #pragma unroll
  for (int j = y4; j < 32; j += 8)
    dst[(size_t)(n0 + j) * K + k0 + x] = (__bf16)tl[x][j];
}

// ---------------- GEMM: C[M,N] = A[M,K] @ BT[N,K]^T + bias ------------------
// m97 structure: 128xBN tile, BK=64, global_load_lds(16B) with pre-swizzled
// source (rule #21), swizzled ds_read_b128.
// EPI: 0 bf16 store, 1 bf16 relu store, 2 f32 store, 3 bf16 store + V-section
//      written transposed to Vtp (QKV gemm only).
template <int EPI, int BN>
__global__ __launch_bounds__(256, 2) void gemm_bt(
    const __bf16* __restrict__ A0, const __bf16* __restrict__ A1, const __bf16* __restrict__ A2,
    const __bf16* __restrict__ BT,
    const float* __restrict__ bias0, const float* __restrict__ bias1, const float* __restrict__ bias2,
    void* __restrict__ Cp, __bf16* __restrict__ Vtp, int M, int N, int K, int nsplit) {
  constexpr int NFR = BN / 32;
  constexpr int WCW = BN / 2;
  constexpr int BI  = BN / 32;
  __shared__ __align__(16) __bf16 As[128 * 64];
  __shared__ __align__(16) __bf16 Bs[BN * 64];
  int tid = threadIdx.x, lane = tid & 63;
  int wave = tid >> 6;
  int wr = (wave >> 1) * 64, wc = (wave & 1) * WCW;

  int gx = N / BN;
  int nwg = gridDim.x;
  int cpx = nwg >> 3;
  int swz = (blockIdx.x & 7) * cpx + (blockIdx.x >> 3);
  int bx = swz % gx, by = swz / gx;
  int row0 = by << 7, col0 = bx * BN;

  int asel = col0 / nsplit;
  const __bf16* A = asel == 0 ? A0 : (asel == 1 ? A1 : A2);
  const float* bias = asel == 0 ? bias0 : (asel == 1 ? bias1 : bias2);

  f32x4 acc[4][NFR] = {};

  for (int kt = 0; kt < K; kt += 64) {
    #pragma unroll
    for (int i = 0; i < 4; ++i) {
      int t = i * 256 + tid;
      int r = t >> 3, cL = t & 7;
      int cS = cL ^ (r & 7);
      gld_lds16(A + (size_t)(row0 + r) * K + kt + cS * 8, As + t * 8);
    }
    #pragma unroll
    for (int i = 0; i < BI; ++i) {
      int t = i * 256 + tid;
      int r = t >> 3, cL = t & 7;
      int cS = cL ^ (r & 7);
      gld_lds16(BT + (size_t)(col0 + r) * K + kt + cS * 8, Bs + t * 8);
    }
    __syncthreads();
    #pragma unroll
    for (int ks = 0; ks < 2; ++ks) {
      bf16x8 af[4], bfr[NFR];
      #pragma unroll
      for (int m = 0; m < 4; ++m) {
        int r = wr + m * 16 + (lane & 15);
        int c = (ks * 4 + (lane >> 4)) ^ (r & 7);
        af[m] = *(const bf16x8*)(As + r * 64 + c * 8);
      }
      #pragma unroll
      for (int n = 0; n < NFR; ++n) {
        int r = wc + n * 16 + (lane & 15);
        int c = (ks * 4 + (lane >> 4)) ^ (r & 7);
        bfr[n] = *(const bf16x8*)(Bs + r * 64 + c * 8);
      }
      #pragma unroll
      for (int m = 0; m < 4; ++m)
        #pragma unroll
        for (int n = 0; n < NFR; ++n)
          acc[m][n] = __builtin_amdgcn_mfma_f32_16x16x32_bf16(af[m], bfr[n], acc[m][n], 0, 0, 0);
    }
    __syncthreads();
  }

  // epilogue: C row = (lane>>4)*4 + j, col = lane&15  (m89-verified layout)
  int rb = row0 + wr + ((lane >> 4) << 2);
  int cb = col0 + wc + (lane & 15);
  if (EPI == 3 && asel == 2) {
    // V panel: write transposed into Vt[(b*8+h)*64+d][n], packed 4 rows (8B)
    int bb = row0 >> 10;
    #pragma unroll
    for (int n = 0; n < NFR; ++n) {
      int c = cb + n * 16;                    // global col in [1024,1536)
      int d = c & 63, hh = (c >> 6) & 7;
      float bv = bias[c % nsplit];
      size_t vbase = ((size_t)((bb * 8 + hh) * 64 + d)) << 10;
      #pragma unroll
      for (int m = 0; m < 4; ++m) {
        int r0 = (rb + m * 16) & 1023;
        ushort4 pk;
        pk.x = bfb(acc[m][n][0] + bv);
        pk.y = bfb(acc[m][n][1] + bv);
        pk.z = bfb(acc[m][n][2] + bv);
        pk.w = bfb(acc[m][n][3] + bv);
        *(ushort4*)((__bf16*)Vtp + vbase + r0) = pk;
      }
    }
    return;
  }
  #pragma unroll
  for (int n = 0; n < NFR; ++n) {
    int c = cb + n * 16;
    float bv = bias[c % nsplit];
    #pragma unroll
    for (int m = 0; m < 4; ++m) {
      #pragma unroll
      for (int j = 0; j < 4; ++j) {
        int r = rb + m * 16 + j;
        float v = acc[m][n][j] + bv;
        if (EPI == 1) v = fmaxf(v, 0.f);
        if (EPI == 2) ((float*)Cp)[(size_t)r * N + c] = v;
        else          ((__bf16*)Cp)[(size_t)r * N + c] = (__bf16)v;
      }
    }
  }
}

// ---------------- fused attention v5: BARRIER-FREE k-loop --------------------
// m169 lesson: K/V per (b,h) = 256KB -> L2-resident (16 blocks share it on one
// XCD via T1 swizzle). So no LDS staging for K/V at all: fragments are read
// directly from global into registers, prefetched 1 phase ahead (K/V, L2 lat)
// and 3 phases ahead (rgw, HBM lat). The 16-phase loop has NO barriers; the
// compiler's precise register-dependency vmcnt insertion does all waiting.
// P goes through per-wave LDS (lgkmcnt only). setprio around MFMA (T5).
__global__ __launch_bounds__(256, 2) void attn_kernel(
    const __bf16* __restrict__ QKV, const __bf16* __restrict__ Vt,
    const float* __restrict__ rgw, __bf16* __restrict__ O) {
  __shared__ __align__(16) __bf16 Qs[64 * 64];
  __shared__ __align__(16) __bf16 Ps[4][16 * 64];

  int tid = threadIdx.x, lane = tid & 63, wave = tid >> 6;
  int flat = (blockIdx.x & 7) * 128 + (blockIdx.x >> 3);   // bijective XCD swz
  int qt = flat & 15, h = (flat >> 4) & 7, b = flat >> 7;
  int q0 = qt * 64;
  const int g = lane >> 4, u = lane & 15;

  // per-lane fragment bases (row part includes u; col chunk includes g)
  const __bf16* kbase = QKV + (size_t)(b * N_ + u) * QKV_LD + DM + h * 64 + g * 8;
  const __bf16* vbase = Vt + (size_t)((b * H_ + h) * 64 + u) * N_ + g * 8;
  const float*  rgw_p = rgw +
      ((size_t)(b * H_ + h) * N_ + (size_t)(q0 + wave * 16 + u)) * N_ + g * 4;

#define LOADK(KF, T)                                                           \
  { _Pragma("unroll")                                                          \
    for (int ks = 0; ks < 2; ++ks)                                             \
      _Pragma("unroll")                                                        \
      for (int n = 0; n < 4; ++n)                                              \
        KF[ks][n] = *(const bf16x8*)(kbase + (size_t)((T) * 64 + n * 16) * QKV_LD + ks * 32); }
#define LOADV(VF, T)                                                           \
  { _Pragma("unroll")                                                          \
    for (int ks = 0; ks < 2; ++ks)                                             \
      _Pragma("unroll")                                                        \
      for (int n = 0; n < 4; ++n)                                              \
        VF[ks][n] = *(const bf16x8*)(vbase + (size_t)(n * 16) * N_ + (T) * 64 + ks * 32); }
#define LOADW(W, T)                                                            \
  { _Pragma("unroll")                                                          \
    for (int n = 0; n < 4; ++n)                                                \
      W[n] = __builtin_nontemporal_load((const f32x4*)(rgw_p + (size_t)(T) * 64 + n * 16)); }

  // ---- prologue ----
  #pragma unroll
  for (int i = 0; i < 2; ++i) {
    int t = i * 256 + tid;
    int r = t >> 3, cL = t & 7, cS = cL ^ (r & 7);
    gld_lds16(QKV + (size_t)(b * N_ + q0 + r) * QKV_LD + h * 64 + cS * 8, Qs + t * 8);
  }
  bf16x8 kfA[2][4], kfB[2][4], vfA[2][4], vfB[2][4];
  f32x4 wA[4], wB[4], wC[4];
  LOADK(kfA, 0) LOADV(vfA, 0)
  LOADW(wA, 0) LOADW(wB, 1) LOADW(wC, 2)
  __syncthreads();                        // Qs ready (compiler drains vmcnt)
  bf16x8 qf[2];
  {
    int r = wave * 16 + u;
    #pragma unroll
    for (int ks = 0; ks < 2; ++ks) {
      int c = (ks * 4 + g) ^ (r & 7);
      qf[ks] = *(const bf16x8*)(Qs + r * 64 + c * 8);
    }
  }

  float l = 0.f;
  f32x4 oacc[4] = {};
  __bf16* pw = &Ps[wave][0];
  union Pk { __bf16 h4[4]; unsigned long long q; };

#define PHASE(T, KC, KN, VC, VN, WCON, DOK, DOV, DOW)                          \
  {                                                                            \
    /* S^T = K @ Q (lane: q-row u, att-cols n*16+g*4+j) */                     \
    f32x4 s[4] = {};                                                           \
    __builtin_amdgcn_s_setprio(1);                                             \
    _Pragma("unroll")                                                          \
    for (int ks = 0; ks < 2; ++ks)                                             \
      _Pragma("unroll")                                                        \
      for (int n = 0; n < 4; ++n)                                              \
        s[n] = __builtin_amdgcn_mfma_f32_16x16x32_bf16(KC[ks][n], qf[ks], s[n], 0, 0, 0); \
    __builtin_amdgcn_s_setprio(0);                                             \
    __builtin_amdgcn_sched_barrier(0);                                         \
    if (DOK) { LOADK(KN, (T) + 1) }                                            \
    __builtin_amdgcn_sched_barrier(0);                                         \
    /* softmax: p = clip(w)*exp(s); P -> per-wave LDS */                       \
    _Pragma("unroll")                                                          \
    for (int n = 0; n < 4; ++n) {                                              \
      Pk pk;                                                                   \
      _Pragma("unroll")                                                        \
      for (int j = 0; j < 4; ++j) {                                            \
        float pv = fmaxf(WCON[n][j], 1e-6f) * exp2f(s[n][j] * SCL);            \
        l += pv;                                                               \
        pk.h4[j] = (__bf16)pv;                                                 \
      }                                                                        \
      int bcol = 2 * n + (g >> 1);                                             \
      *(unsigned long long*)(pw + u * 64 + ((bcol ^ (u & 7)) << 3) + ((g & 1) << 2)) = pk.q; \
    }                                                                          \
    __builtin_amdgcn_sched_barrier(0);                                         \
    if (DOW) { LOADW(WCON, (T) + 3) }                                          \
    __builtin_amdgcn_sched_barrier(0);                                         \
    /* O += P @ V */                                                           \
    __builtin_amdgcn_s_setprio(1);                                             \
    _Pragma("unroll")                                                          \
    for (int ks = 0; ks < 2; ++ks) {                                           \
      int cp = (ks * 4 + g) ^ (u & 7);                                         \
      bf16x8 pa = *(const bf16x8*)(pw + u * 64 + cp * 8);                      \
      _Pragma("unroll")                                                        \
      for (int n = 0; n < 4; ++n)                                              \
        oacc[n] = __builtin_amdgcn_mfma_f32_16x16x32_bf16(pa, VC[ks][n], oacc[n], 0, 0, 0); \
    }                                                                          \
    __builtin_amdgcn_s_setprio(0);                                             \
    __builtin_amdgcn_sched_barrier(0);                                         \
    if (DOV) { LOADV(VN, (T) + 1) }                                            \
    __builtin_amdgcn_sched_barrier(0);                                         \
  }

  PHASE(0,  kfA, kfB, vfA, vfB, wA, 1, 1, 1)
  PHASE(1,  kfB, kfA, vfB, vfA, wB, 1, 1, 1)
  PHASE(2,  kfA, kfB, vfA, vfB, wC, 1, 1, 1)
  PHASE(3,  kfB, kfA, vfB, vfA, wA, 1, 1, 1)
  PHASE(4,  kfA, kfB, vfA, vfB, wB, 1, 1, 1)
  PHASE(5,  kfB, kfA, vfB, vfA, wC, 1, 1, 1)
  PHASE(6,  kfA, kfB, vfA, vfB, wA, 1, 1, 1)
  PHASE(7,  kfB, kfA, vfB, vfA, wB, 1, 1, 1)
  PHASE(8,  kfA, kfB, vfA, vfB, wC, 1, 1, 1)
  PHASE(9,  kfB, kfA, vfB, vfA, wA, 1, 1, 1)
  PHASE(10, kfA, kfB, vfA, vfB, wB, 1, 1, 1)
  PHASE(11, kfB, kfA, vfB, vfA, wC, 1, 1, 1)
  PHASE(12, kfA, kfB, vfA, vfB, wA, 1, 1, 1)
  PHASE(13, kfB, kfA, vfB, vfA, wB, 1, 1, 0)
  PHASE(14, kfA, kfB, vfA, vfB, wC, 1, 1, 0)
  PHASE(15, kfB, kfA, vfB, vfA, wA, 0, 0, 0)
#undef PHASE
#undef LOADK
#undef LOADV
#undef LOADW

  // row-sum: partials per lane (row u); sum across the 4 g-groups
  l += __shfl_xor(l, 16);
  l += __shfl_xor(l, 32);
  float linv[4];
  #pragma unroll
  for (int j = 0; j < 4; ++j)
    linv[j] = 1.f / __shfl(l, (lane & 48) | (g * 4 + j));

  int orow = b * N_ + q0 + wave * 16 + g * 4;
  int ocol = h * 64 + u;
  #pragma unroll
  for (int j = 0; j < 4; ++j)
    #pragma unroll
    for (int n = 0; n < 4; ++n)
      O[(size_t)(orow + j) * DM + ocol + n * 16] = (__bf16)(oacc[n][j] * linv[j]);
}

// ---------------- LayerNorm(x1 + x2), optional bf16 copy --------------------
template <int WRITE_BF>
__global__ __launch_bounds__(256) void ln_kernel(
    const float* __restrict__ x1, const float* __restrict__ x2,
    const float* __restrict__ gw, const float* __restrict__ bw,
    float* __restrict__ outf, __bf16* __restrict__ outb) {
  __shared__ float red[8];
  int row = blockIdx.x, t = threadIdx.x;
  size_t base = (size_t)row * DM;
  float v0 = x1[base + t] + x2[base + t];
  float v1 = x1[base + t + 256] + x2[base + t + 256];
  float s = v0 + v1, s2 = v0 * v0 + v1 * v1;
  #pragma unroll
  for (int o = 32; o; o >>= 1) { s += __shfl_xor(s, o); s2 += __shfl_xor(s2, o); }
  int wave = t >> 6;
  if ((t & 63) == 0) { red[wave] = s; red[4 + wave] = s2; }
  __syncthreads();
  s = red[0] + red[1] + red[2] + red[3];
  s2 = red[4] + red[5] + red[6] + red[7];
  float mu = s * (1.f / DM);
  float var = s2 * (1.f / DM) - mu * mu;
  float rstd = rsqrtf(var + 1e-5f);
  float y0 = (v0 - mu) * rstd * gw[t] + bw[t];
  float y1 = (v1 - mu) * rstd * gw[t + 256] + bw[t + 256];
  outf[base + t] = y0;
  outf[base + t + 256] = y1;
  if (WRITE_BF) {
    outb[base + t] = (__bf16)y0;
    outb[base + t + 256] = (__bf16)y1;
  }
}

// ---------------- launch -----------------------------------------------------
extern "C" void kernel_launch(void* const* d_in, const int* in_sizes, int n_in,
                              void* d_out, int out_size, void* d_ws, size_t ws_size,
                              hipStream_t stream) {
  const float* queries = (const float*)d_in[0];
  const float* keys    = (const float*)d_in[1];
  const float* values  = (const float*)d_in[2];
  const float* rgw     = (const float*)d_in[3];
  const float* pos     = (const float*)d_in[4];
  const float* Wq = (const float*)d_in[5];
  const float* bq = (const float*)d_in[6];
  const float* Wk = (const float*)d_in[7];
  const float* bk = (const float*)d_in[8];
  const float* Wv = (const float*)d_in[9];
  const float* bv = (const float*)d_in[10];
  const float* Wo = (const float*)d_in[11];
  const float* bo = (const float*)d_in[12];
  const float* ln1g = (const float*)d_in[13];
  const float* ln1b = (const float*)d_in[14];
  const float* W1 = (const float*)d_in[15];
  const float* b1 = (const float*)d_in[16];
  const float* W2 = (const float*)d_in[17];
  const float* b2 = (const float*)d_in[18];
  const float* ln2g = (const float*)d_in[19];
  const float* ln2b = (const float*)d_in[20];
  float* out = (float*)d_out;

  char* ws = (char*)d_ws;
  const size_t SZX = (size_t)ROWS * DM * 2;        // 8 MB (bf16 8192x512)
  __bf16* Xq    = (__bf16*)(ws);
  __bf16* Xk    = (__bf16*)(ws + SZX);
  __bf16* Xv    = (__bf16*)(ws + 2 * SZX);
  __bf16* WqkvT = (__bf16*)(ws + 3 * SZX);                       // 1536x512
  __bf16* WoT   = (__bf16*)(ws + 3 * SZX + 1572864);             // 512x512
  __bf16* W1T   = (__bf16*)(ws + 3 * SZX + 2097152);             // 2048x512
  __bf16* W2T   = (__bf16*)(ws + 3 * SZX + 4194304);             // 512x2048
  __bf16* QKV   = (__bf16*)(ws + 3 * SZX + 6291456);             // 8192x1536
  __bf16* Vt    = (__bf16*)(ws + 3 * SZX + 6291456 + 3 * SZX);   // (B,H,64,N)
  __bf16* Oat   = (__bf16*)(ws + 3 * SZX + 6291456 + 4 * SZX);
  // aliases over dead regions:
  float*  attproj = (float*)Xq;     // 16 MB over Xq+Xk (dead after QKV GEMM)
  __bf16* attoutb = Xv;             // over Xv (dead after QKV GEMM)
  float*  attoutf = (float*)QKV;    // over QKV (dead after attention)
  float*  ff2     = (float*)Vt;     // over Vt+Oat (dead after Wo GEMM)
  __bf16* ff1     = (__bf16*)(ws + 3 * SZX + 6291456 + 5 * SZX); // 8192x2048

  prep_and_wt<<<4096 + 3072, 256, 0, stream>>>(
      queries, keys, values, pos, Xq, Xk, Xv,
      Wq, Wk, Wv, Wo, W1, W2, WqkvT, WoT, W1T, W2T);

  // QKV: C[8192,1536]; V panel goes straight to Vt (transposed)
  gemm_bt<3, 128><<<(ROWS / 128) * (QKV_LD / 128), 256, 0, stream>>>(
      Xq, Xk, Xv, WqkvT, bq, bk, bv, QKV, Vt, ROWS, QKV_LD, DM, DM);

  attn_kernel<<<B_ * H_ * (N_ / 64), 256, 0, stream>>>(QKV, Vt, rgw, Oat);

  gemm_bt<2, 64><<<(ROWS / 128) * (DM / 64), 256, 0, stream>>>(
      Oat, Oat, Oat, WoT, bo, bo, bo, attproj, nullptr, ROWS, DM, DM, DM);

  ln_kernel<1><<<ROWS, 256, 0, stream>>>(queries, attproj, ln1g, ln1b, attoutf, attoutb);

  gemm_bt<1, 128><<<(ROWS / 128) * (DFF / 128), 256, 0, stream>>>(
      attoutb, attoutb, attoutb, W1T, b1, b1, b1, ff1, nullptr, ROWS, DFF, DM, DFF);

  gemm_bt<2, 64><<<(ROWS / 128) * (DM / 64), 256, 0, stream>>>(
      ff1, ff1, ff1, W2T, b2, b2, b2, ff2, nullptr, ROWS, DM, DFF, DM);

  ln_kernel<0><<<ROWS, 256, 0, stream>>>(attoutf, ff2, ln2g, ln2b, out, nullptr);
}

// Round 8
// 223.873 us; speedup vs baseline: 1.2736x; 1.2736x over previous
//
#include <hip/hip_runtime.h>
#include <hip/hip_bf16.h>
#include <stdint.h>

// EncoderLayer: B=8 N=1024 D=512 H=8 Dh=64 FF=2048
#define B_   8
#define N_   1024
#define DM   512
#define H_   8
#define DFF  2048
#define ROWS (B_ * N_)          // 8192
#define QKV_LD (3 * DM)         // 1536
#define LOG2E 1.4426950408889634f
#define SCL  (0.125f * LOG2E)   // att scale 1/8 folded into exp2

typedef __bf16 bf16x8 __attribute__((ext_vector_type(8)));
typedef float  f32x4  __attribute__((ext_vector_type(4)));

__device__ __forceinline__ void gld_lds16(const void* g, void* l) {
  __builtin_amdgcn_global_load_lds((__attribute__((address_space(1))) void*)g,
                                   (__attribute__((address_space(3))) void*)l, 16, 0, 0);
}

__device__ __forceinline__ unsigned short bfb(float x) {
  __bf16 h = (__bf16)x;
  unsigned short u;
  __builtin_memcpy(&u, &h, 2);
  return u;
}

// ------- fused: prep (x_q=q+pos etc -> bf16) + all weight transposes --------
__global__ __launch_bounds__(256) void prep_and_wt(
    const float* __restrict__ q, const float* __restrict__ k,
    const float* __restrict__ v, const float* __restrict__ pos,
    __bf16* __restrict__ xq, __bf16* __restrict__ xk, __bf16* __restrict__ xv,
    const float* __restrict__ Wq, const float* __restrict__ Wk,
    const float* __restrict__ Wv, const float* __restrict__ Wo,
    const float* __restrict__ W1, const float* __restrict__ W2,
    __bf16* __restrict__ WqkvT, __bf16* __restrict__ WoT,
    __bf16* __restrict__ W1T, __bf16* __restrict__ W2T) {
  __shared__ float tl[32][33];
  if (blockIdx.x < 4096) {                    // ---- prep part
    int i = blockIdx.x * 256 + threadIdx.x;   // float4 group
    float4 pv = ((const float4*)pos)[i];
    float4 qv = ((const float4*)q)[i];
    float4 kv = ((const float4*)k)[i];
    float4 vv = ((const float4*)v)[i];
    ushort4 o;
    o.x = bfb(qv.x + pv.x); o.y = bfb(qv.y + pv.y); o.z = bfb(qv.z + pv.z); o.w = bfb(qv.w + pv.w);
    ((ushort4*)xq)[i] = o;
    o.x = bfb(kv.x + pv.x); o.y = bfb(kv.y + pv.y); o.z = bfb(kv.z + pv.z); o.w = bfb(kv.w + pv.w);
    ((ushort4*)xk)[i] = o;
    o.x = bfb(vv.x); o.y = bfb(vv.y); o.z = bfb(vv.z); o.w = bfb(vv.w);
    ((ushort4*)xv)[i] = o;
    return;
  }
  int idx = blockIdx.x - 4096;                // ---- weight transpose part
  const float* src; __bf16* dst; int K, N, t;
  if (idx < 768) {
    src = idx < 256 ? Wq : (idx < 512 ? Wk : Wv);
    dst = WqkvT + (size_t)(idx >> 8) * 512 * 512;
    K = 512; N = 512; t = idx & 255;
  } else if (idx < 1024) { src = Wo; dst = WoT;  K = 512;  N = 512;  t = idx - 768; }
  else if (idx < 2048)   { src = W1; dst = W1T;  K = 512;  N = 2048; t = idx - 1024; }
  else                   { src = W2; dst = W2T;  K = 2048; N = 512;  t = idx - 2048; }
  int tiles_n = N >> 5;
  int tn = t & (tiles_n - 1), tk = t / tiles_n;
  int n0 = tn * 32, k0 = tk * 32;
  int x = threadIdx.x & 31, y4 = threadIdx.x >> 5;
  #pragma unroll
  for (int j = y4; j < 32; j += 8) tl[j][x] = src[(size_t)(k0 + j) * N + n0 + x];
  __syncthreads();
  #pragma unroll
  for (int j = y4; j < 32; j += 8)
    dst[(size_t)(n0 + j) * K + k0 + x] = (__bf16)tl[x][j];
}

// ---------------- GEMM: C[M,N] = A[M,K] @ BT[N,K]^T + bias ------------------
// 2-phase pipelined (T3 minimum + T4 counted vmcnt): double-buffered LDS,
// stage tile t+1 before computing tile t, vmcnt(NLD) drains only tile t,
// raw s_barrier pair per K-step (no full drain — loads stay in flight).
// EPI: 0 bf16 store, 1 bf16 relu store, 2 f32 store, 3 bf16 store + V-section
//      written transposed to Vtp (QKV gemm only).
template <int EPI, int BN>
__global__ __launch_bounds__(256, 2) void gemm_bt(
    const __bf16* __restrict__ A0, const __bf16* __restrict__ A1, const __bf16* __restrict__ A2,
    const __bf16* __restrict__ BT,
    const float* __restrict__ bias0, const float* __restrict__ bias1, const float* __restrict__ bias2,
    void* __restrict__ Cp, __bf16* __restrict__ Vtp, int M, int N, int K, int nsplit) {
  constexpr int NFR = BN / 32;          // B frags per wave
  constexpr int WCW = BN / 2;           // wave col width
  constexpr int BI  = BN / 32;          // B staging instrs per thread
  __shared__ __align__(16) __bf16 As[2][128 * 64];
  __shared__ __align__(16) __bf16 Bs[2][BN * 64];
  int tid = threadIdx.x, lane = tid & 63;
  int wave = tid >> 6;
  int wr = (wave >> 1) * 64, wc = (wave & 1) * WCW;

  int gx = N / BN;
  int nwg = gridDim.x;
  int cpx = nwg >> 3;
  int swz = (blockIdx.x & 7) * cpx + (blockIdx.x >> 3);
  int bx = swz % gx, by = swz / gx;
  int row0 = by << 7, col0 = bx * BN;

  int asel = col0 / nsplit;
  const __bf16* A = asel == 0 ? A0 : (asel == 1 ? A1 : A2);
  const float* bias = asel == 0 ? bias0 : (asel == 1 ? bias1 : bias2);

  f32x4 acc[4][NFR] = {};

#define GSTAGE(BUF, KT)                                                        \
  { _Pragma("unroll")                                                          \
    for (int i = 0; i < 4; ++i) {                                              \
      int t = i * 256 + tid;                                                   \
      int r = t >> 3, cS = (t & 7) ^ (r & 7);                                  \
      gld_lds16(A + (size_t)(row0 + r) * K + (KT) + cS * 8, As[BUF] + t * 8);  \
    }                                                                          \
    _Pragma("unroll")                                                          \
    for (int i = 0; i < BI; ++i) {                                             \
      int t = i * 256 + tid;                                                   \
      int r = t >> 3, cS = (t & 7) ^ (r & 7);                                  \
      gld_lds16(BT + (size_t)(col0 + r) * K + (KT) + cS * 8, Bs[BUF] + t * 8); \
    } }

#define GCOMP(BUF)                                                             \
  { const __bf16* Asc = As[BUF];                                               \
    const __bf16* Bsc = Bs[BUF];                                               \
    _Pragma("unroll")                                                          \
    for (int ks = 0; ks < 2; ++ks) {                                           \
      bf16x8 af[4], bfr[NFR];                                                  \
      _Pragma("unroll")                                                        \
      for (int m = 0; m < 4; ++m) {                                            \
        int r = wr + m * 16 + (lane & 15);                                     \
        int c = (ks * 4 + (lane >> 4)) ^ (r & 7);                              \
        af[m] = *(const bf16x8*)(Asc + r * 64 + c * 8);                        \
      }                                                                        \
      _Pragma("unroll")                                                        \
      for (int n = 0; n < NFR; ++n) {                                          \
        int r = wc + n * 16 + (lane & 15);                                     \
        int c = (ks * 4 + (lane >> 4)) ^ (r & 7);                              \
        bfr[n] = *(const bf16x8*)(Bsc + r * 64 + c * 8);                       \
      }                                                                        \
      _Pragma("unroll")                                                        \
      for (int m = 0; m < 4; ++m)                                              \
        _Pragma("unroll")                                                      \
        for (int n = 0; n < NFR; ++n)                                          \
          acc[m][n] = __builtin_amdgcn_mfma_f32_16x16x32_bf16(af[m], bfr[n], acc[m][n], 0, 0, 0); \
    } }

  GSTAGE(0, 0)
  int cur = 0;
  for (int kt = 64; kt < K; kt += 64) {
    GSTAGE(cur ^ 1, kt)
    if constexpr (BN == 128) asm volatile("s_waitcnt vmcnt(8)" ::: "memory");
    else                     asm volatile("s_waitcnt vmcnt(6)" ::: "memory");
    __builtin_amdgcn_s_barrier();
    __builtin_amdgcn_sched_barrier(0);
    GCOMP(cur)
    __builtin_amdgcn_s_barrier();     // protect buf[cur] from next stage
    cur ^= 1;
  }
  asm volatile("s_waitcnt vmcnt(0)" ::: "memory");
  __builtin_amdgcn_s_barrier();
  __builtin_amdgcn_sched_barrier(0);
  GCOMP(cur)
#undef GSTAGE
#undef GCOMP

  // epilogue: C row = (lane>>4)*4 + j, col = lane&15  (m89-verified layout)
  int rb = row0 + wr + ((lane >> 4) << 2);
  int cb = col0 + wc + (lane & 15);
  if (EPI == 3 && asel == 2) {
    // V panel: write transposed into Vt[(b*8+h)*64+d][n], packed 4 rows (8B)
    int bb = row0 >> 10;
    #pragma unroll
    for (int n = 0; n < NFR; ++n) {
      int c = cb + n * 16;                    // global col in [1024,1536)
      int d = c & 63, hh = (c >> 6) & 7;
      float bv = bias[c % nsplit];
      size_t vbase = ((size_t)((bb * 8 + hh) * 64 + d)) << 10;
      #pragma unroll
      for (int m = 0; m < 4; ++m) {
        int r0 = (rb + m * 16) & 1023;
        ushort4 pk;
        pk.x = bfb(acc[m][n][0] + bv);
        pk.y = bfb(acc[m][n][1] + bv);
        pk.z = bfb(acc[m][n][2] + bv);
        pk.w = bfb(acc[m][n][3] + bv);
        *(ushort4*)((__bf16*)Vtp + vbase + r0) = pk;
      }
    }
    return;
  }
  #pragma unroll
  for (int n = 0; n < NFR; ++n) {
    int c = cb + n * 16;
    float bv = bias[c % nsplit];
    #pragma unroll
    for (int m = 0; m < 4; ++m) {
      #pragma unroll
      for (int j = 0; j < 4; ++j) {
        int r = rb + m * 16 + j;
        float v = acc[m][n][j] + bv;
        if (EPI == 1) v = fmaxf(v, 0.f);
        if (EPI == 2) ((float*)Cp)[(size_t)r * N + c] = v;
        else          ((__bf16*)Cp)[(size_t)r * N + c] = (__bf16)v;
      }
    }
  }
}

// ---------------- fused attention (R6-measured version) ----------------------
// softmax(log(clip(w)) + s) == normalize(clip(w) * exp(s)) exactly.
// SWAPPED QK^T: mfma(K,Q) -> lane owns q-row u, att-cols n*16+g*4+{0..3}.
// rgw: 4-deep register buffers, nontemporal dwordx4 loads issued at PHASE TOP
// with KV-first queue order so vmcnt(4) drains KV without touching rgw slack
// (2 full phases guaranteed). K/V double-buffered LDS, one barrier per phase,
// counted vmcnt (T3/T4), setprio around MFMA clusters (T5), XCD swizzle (T1).
__global__ __launch_bounds__(256, 3) void attn_kernel(
    const __bf16* __restrict__ QKV, const __bf16* __restrict__ Vt,
    const float* __restrict__ rgw, __bf16* __restrict__ O) {
  __shared__ __align__(16) __bf16 Qs[64 * 64];
  __shared__ __align__(16) __bf16 Ks[2][64 * 64];
  __shared__ __align__(16) __bf16 Vs[2][64 * 64];
  __shared__ __align__(16) __bf16 Ps[4][16 * 64];

  int tid = threadIdx.x, lane = tid & 63, wave = tid >> 6;
  int flat = (blockIdx.x & 7) * 128 + (blockIdx.x >> 3);   // bijective XCD swz
  int qt = flat & 15, h = (flat >> 4) & 7, b = flat >> 7;
  int q0 = qt * 64;
  const int g = lane >> 4, u = lane & 15;

  // lane's q-row = q0 + wave*16 + u; att-col chunk starts at g*4
  const float* rgw_p = rgw +
      ((size_t)(b * H_ + h) * N_ + (size_t)(q0 + wave * 16 + u)) * N_ + g * 4;

#define STAGE_KV(BUF, KT)                                                      \
  {                                                                            \
    _Pragma("unroll")                                                          \
    for (int i = 0; i < 2; ++i) {                                              \
      int t = i * 256 + tid;                                                   \
      int r = t >> 3, cL = t & 7, cS = cL ^ (r & 7);                           \
      gld_lds16(QKV + (size_t)(b * N_ + (KT) + r) * QKV_LD + DM + h * 64 + cS * 8, Ks[BUF] + t * 8); \
      gld_lds16(Vt + (size_t)((b * H_ + h) * 64 + r) * N_ + (KT) + cS * 8, Vs[BUF] + t * 8);         \
    }                                                                          \
  }
#define RPF(W, T)                                                              \
  {                                                                            \
    _Pragma("unroll")                                                          \
    for (int n = 0; n < 4; ++n)                                                \
      W[n] = __builtin_nontemporal_load((const f32x4*)(rgw_p + (size_t)(T) * 64 + n * 16)); \
  }

  // ---- prologue: Q + KV[0] -> LDS; rgw tiles 0..2 -> registers ----
  #pragma unroll
  for (int i = 0; i < 2; ++i) {
    int t = i * 256 + tid;
    int r = t >> 3, cL = t & 7, cS = cL ^ (r & 7);
    gld_lds16(QKV + (size_t)(b * N_ + q0 + r) * QKV_LD + h * 64 + cS * 8, Qs + t * 8);
  }
  STAGE_KV(0, 0)
  __builtin_amdgcn_sched_barrier(0);
  f32x4 wA[4], wB[4], wC[4], wD[4];
  RPF(wA, 0) RPF(wB, 1) RPF(wC, 2)
  __builtin_amdgcn_sched_barrier(0);

  float l = 0.f;
  f32x4 oacc[4] = {};
  bf16x8 qf[2];
  __bf16* pw = &Ps[wave][0];

  union Pk { __bf16 h4[4]; unsigned long long q; };

#define PHASE(T16, WAITSTR, DOSTAGE, DORPF, WCON, WPF)                         \
  {                                                                            \
    asm volatile(WAITSTR ::: "memory");                                        \
    __builtin_amdgcn_s_barrier();                                              \
    if (DOSTAGE) { STAGE_KV(((T16) + 1) & 1, ((T16) + 1) * 64) }               \
    __builtin_amdgcn_sched_barrier(0);                                         \
    if (DORPF) { RPF(WPF, (T16) + 3) }                                         \
    __builtin_amdgcn_sched_barrier(0);                                         \
    if ((T16) == 0) {                                                          \
      int r = wave * 16 + u;                                                   \
      _Pragma("unroll")                                                        \
      for (int ks = 0; ks < 2; ++ks) {                                         \
        int c = (ks * 4 + g) ^ (r & 7);                                        \
        qf[ks] = *(const bf16x8*)(Qs + r * 64 + c * 8);                        \
      }                                                                        \
    }                                                                          \
    f32x4 s[4] = {};                                                           \
    __builtin_amdgcn_s_setprio(1);                                             \
    _Pragma("unroll")                                                          \
    for (int ks = 0; ks < 2; ++ks) {                                           \
      _Pragma("unroll")                                                        \
      for (int n = 0; n < 4; ++n) {                                            \
        int r = n * 16 + u;                                                    \
        int c = (ks * 4 + g) ^ (r & 7);                                        \
        bf16x8 kf = *(const bf16x8*)(Ks[(T16) & 1] + r * 64 + c * 8);          \
        s[n] = __builtin_amdgcn_mfma_f32_16x16x32_bf16(kf, qf[ks], s[n], 0, 0, 0); \
      }                                                                        \
    }                                                                          \
    __builtin_amdgcn_s_setprio(0);                                             \
    _Pragma("unroll")                                                          \
    for (int n = 0; n < 4; ++n) {                                              \
      Pk pk;                                                                   \
      _Pragma("unroll")                                                        \
      for (int j = 0; j < 4; ++j) {                                            \
        float pv = fmaxf(WCON[n][j], 1e-6f) * exp2f(s[n][j] * SCL);            \
        l += pv;                                                               \
        pk.h4[j] = (__bf16)pv;                                                 \
      }                                                                        \
      int bcol = 2 * n + (g >> 1);                                             \
      *(unsigned long long*)(pw + u * 64 + ((bcol ^ (u & 7)) << 3) + ((g & 1) << 2)) = pk.q; \
    }                                                                          \
    __builtin_amdgcn_s_setprio(1);                                             \
    _Pragma("unroll")                                                          \
    for (int ks = 0; ks < 2; ++ks) {                                           \
      int cp = (ks * 4 + g) ^ (u & 7);                                         \
      bf16x8 pa = *(const bf16x8*)(pw + u * 64 + cp * 8);                      \
      _Pragma("unroll")                                                        \
      for (int n = 0; n < 4; ++n) {                                            \
        int r = n * 16 + u;                                                    \
        int c = (ks * 4 + g) ^ (r & 7);                                        \
        bf16x8 vb = *(const bf16x8*)(Vs[(T16) & 1] + r * 64 + c * 8);          \
        oacc[n] = __builtin_amdgcn_mfma_f32_16x16x32_bf16(pa, vb, oacc[n], 0, 0, 0); \
      }                                                                        \
    }                                                                          \
    __builtin_amdgcn_s_setprio(0);                                             \
  }

  PHASE(0,  "s_waitcnt vmcnt(12)", 1, 1, wA, wD)
  PHASE(1,  "s_waitcnt vmcnt(4)",  1, 1, wB, wA)
  PHASE(2,  "s_waitcnt vmcnt(4)",  1, 1, wC, wB)
  PHASE(3,  "s_waitcnt vmcnt(4)",  1, 1, wD, wC)
  PHASE(4,  "s_waitcnt vmcnt(4)",  1, 1, wA, wD)
  PHASE(5,  "s_waitcnt vmcnt(4)",  1, 1, wB, wA)
  PHASE(6,  "s_waitcnt vmcnt(4)",  1, 1, wC, wB)
  PHASE(7,  "s_waitcnt vmcnt(4)",  1, 1, wD, wC)
  PHASE(8,  "s_waitcnt vmcnt(4)",  1, 1, wA, wD)
  PHASE(9,  "s_waitcnt vmcnt(4)",  1, 1, wB, wA)
  PHASE(10, "s_waitcnt vmcnt(4)",  1, 1, wC, wB)
  PHASE(11, "s_waitcnt vmcnt(4)",  1, 1, wD, wC)
  PHASE(12, "s_waitcnt vmcnt(4)",  1, 1, wA, wD)
  PHASE(13, "s_waitcnt vmcnt(4)",  1, 0, wB, wA)
  PHASE(14, "s_waitcnt vmcnt(0)",  1, 0, wC, wB)
  PHASE(15, "s_waitcnt vmcnt(0)",  0, 0, wD, wC)
#undef PHASE
#undef STAGE_KV
#undef RPF

  // row-sum: partials per lane (row u); sum across the 4 g-groups
  l += __shfl_xor(l, 16);
  l += __shfl_xor(l, 32);
  float linv[4];
  #pragma unroll
  for (int j = 0; j < 4; ++j)
    linv[j] = 1.f / __shfl(l, (lane & 48) | (g * 4 + j));

  int orow = b * N_ + q0 + wave * 16 + g * 4;
  int ocol = h * 64 + u;
  #pragma unroll
  for (int j = 0; j < 4; ++j)
    #pragma unroll
    for (int n = 0; n < 4; ++n)
      O[(size_t)(orow + j) * DM + ocol + n * 16] = (__bf16)(oacc[n][j] * linv[j]);
}

// ---------------- LayerNorm(x1 + x2), optional bf16 copy --------------------
template <int WRITE_BF>
__global__ __launch_bounds__(256) void ln_kernel(
    const float* __restrict__ x1, const float* __restrict__ x2,
    const float* __restrict__ gw, const float* __restrict__ bw,
    float* __restrict__ outf, __bf16* __restrict__ outb) {
  __shared__ float red[8];
  int row = blockIdx.x, t = threadIdx.x;
  size_t base = (size_t)row * DM;
  float v0 = x1[base + t] + x2[base + t];
  float v1 = x1[base + t + 256] + x2[base + t + 256];
  float s = v0 + v1, s2 = v0 * v0 + v1 * v1;
  #pragma unroll
  for (int o = 32; o; o >>= 1) { s += __shfl_xor(s, o); s2 += __shfl_xor(s2, o); }
  int wave = t >> 6;
  if ((t & 63) == 0) { red[wave] = s; red[4 + wave] = s2; }
  __syncthreads();
  s = red[0] + red[1] + red[2] + red[3];
  s2 = red[4] + red[5] + red[6] + red[7];
  float mu = s * (1.f / DM);
  float var = s2 * (1.f / DM) - mu * mu;
  float rstd = rsqrtf(var + 1e-5f);
  float y0 = (v0 - mu) * rstd * gw[t] + bw[t];
  float y1 = (v1 - mu) * rstd * gw[t + 256] + bw[t + 256];
  outf[base + t] = y0;
  outf[base + t + 256] = y1;
  if (WRITE_BF) {
    outb[base + t] = (__bf16)y0;
    outb[base + t + 256] = (__bf16)y1;
  }
}

// ---------------- launch -----------------------------------------------------
extern "C" void kernel_launch(void* const* d_in, const int* in_sizes, int n_in,
                              void* d_out, int out_size, void* d_ws, size_t ws_size,
                              hipStream_t stream) {
  const float* queries = (const float*)d_in[0];
  const float* keys    = (const float*)d_in[1];
  const float* values  = (const float*)d_in[2];
  const float* rgw     = (const float*)d_in[3];
  const float* pos     = (const float*)d_in[4];
  const float* Wq = (const float*)d_in[5];
  const float* bq = (const float*)d_in[6];
  const float* Wk = (const float*)d_in[7];
  const float* bk = (const float*)d_in[8];
  const float* Wv = (const float*)d_in[9];
  const float* bv = (const float*)d_in[10];
  const float* Wo = (const float*)d_in[11];
  const float* bo = (const float*)d_in[12];
  const float* ln1g = (const float*)d_in[13];
  const float* ln1b = (const float*)d_in[14];
  const float* W1 = (const float*)d_in[15];
  const float* b1 = (const float*)d_in[16];
  const float* W2 = (const float*)d_in[17];
  const float* b2 = (const float*)d_in[18];
  const float* ln2g = (const float*)d_in[19];
  const float* ln2b = (const float*)d_in[20];
  float* out = (float*)d_out;

  char* ws = (char*)d_ws;
  const size_t SZX = (size_t)ROWS * DM * 2;        // 8 MB (bf16 8192x512)
  __bf16* Xq    = (__bf16*)(ws);
  __bf16* Xk    = (__bf16*)(ws + SZX);
  __bf16* Xv    = (__bf16*)(ws + 2 * SZX);
  __bf16* WqkvT = (__bf16*)(ws + 3 * SZX);                       // 1536x512
  __bf16* WoT   = (__bf16*)(ws + 3 * SZX + 1572864);             // 512x512
  __bf16* W1T   = (__bf16*)(ws + 3 * SZX + 2097152);             // 2048x512
  __bf16* W2T   = (__bf16*)(ws + 3 * SZX + 4194304);             // 512x2048
  __bf16* QKV   = (__bf16*)(ws + 3 * SZX + 6291456);             // 8192x1536
  __bf16* Vt    = (__bf16*)(ws + 3 * SZX + 6291456 + 3 * SZX);   // (B,H,64,N)
  __bf16* Oat   = (__bf16*)(ws + 3 * SZX + 6291456 + 4 * SZX);
  // aliases over dead regions:
  float*  attproj = (float*)Xq;     // 16 MB over Xq+Xk (dead after QKV GEMM)
  __bf16* attoutb = Xv;             // over Xv (dead after QKV GEMM)
  float*  attoutf = (float*)QKV;    // over QKV (dead after attention)
  float*  ff2     = (float*)Vt;     // over Vt+Oat (dead after Wo GEMM)
  __bf16* ff1     = (__bf16*)(ws + 3 * SZX + 6291456 + 5 * SZX); // 8192x2048

  prep_and_wt<<<4096 + 3072, 256, 0, stream>>>(
      queries, keys, values, pos, Xq, Xk, Xv,
      Wq, Wk, Wv, Wo, W1, W2, WqkvT, WoT, W1T, W2T);

  // QKV: C[8192,1536]; V panel goes straight to Vt (transposed)
  gemm_bt<3, 128><<<(ROWS / 128) * (QKV_LD / 128), 256, 0, stream>>>(
      Xq, Xk, Xv, WqkvT, bq, bk, bv, QKV, Vt, ROWS, QKV_LD, DM, DM);

  attn_kernel<<<B_ * H_ * (N_ / 64), 256, 0, stream>>>(QKV, Vt, rgw, Oat);

  gemm_bt<2, 64><<<(ROWS / 128) * (DM / 64), 256, 0, stream>>>(
      Oat, Oat, Oat, WoT, bo, bo, bo, attproj, nullptr, ROWS, DM, DM, DM);

  ln_kernel<1><<<ROWS, 256, 0, stream>>>(queries, attproj, ln1g, ln1b, attoutf, attoutb);

  gemm_bt<1, 128><<<(ROWS / 128) * (DFF / 128), 256, 0, stream>>>(
      attoutb, attoutb, attoutb, W1T, b1, b1, b1, ff1, nullptr, ROWS, DFF, DM, DFF);

  gemm_bt<2, 64><<<(ROWS / 128) * (DM / 64), 256, 0, stream>>>(
      ff1, ff1, ff1, W2T, b2, b2, b2, ff2, nullptr, ROWS, DM, DFF, DM);

  ln_kernel<0><<<ROWS, 256, 0, stream>>>(attoutf, ff2, ln2g, ln2b, out, nullptr);
}

// Round 9
// 210.637 us; speedup vs baseline: 1.3536x; 1.0628x over previous
//
#include <hip/hip_runtime.h>
#include <hip/hip_bf16.h>
#include <stdint.h>

// EncoderLayer: B=8 N=1024 D=512 H=8 Dh=64 FF=2048
#define B_   8
#define N_   1024
#define DM   512
#define H_   8
#define DFF  2048
#define ROWS (B_ * N_)          // 8192
#define QKV_LD (3 * DM)         // 1536
#define LOG2E 1.4426950408889634f
#define SCL  (0.125f * LOG2E)   // att scale 1/8 folded into exp2

typedef __bf16 bf16x8 __attribute__((ext_vector_type(8)));
typedef float  f32x4  __attribute__((ext_vector_type(4)));

__device__ __forceinline__ void gld_lds16(const void* g, void* l) {
  __builtin_amdgcn_global_load_lds((__attribute__((address_space(1))) void*)g,
                                   (__attribute__((address_space(3))) void*)l, 16, 0, 0);
}

__device__ __forceinline__ unsigned short bfb(float x) {
  __bf16 h = (__bf16)x;
  unsigned short u;
  __builtin_memcpy(&u, &h, 2);
  return u;
}

// ------- fused: prep (x_q=q+pos etc -> bf16) + all weight transposes --------
__global__ __launch_bounds__(256) void prep_and_wt(
    const float* __restrict__ q, const float* __restrict__ k,
    const float* __restrict__ v, const float* __restrict__ pos,
    __bf16* __restrict__ xq, __bf16* __restrict__ xk, __bf16* __restrict__ xv,
    const float* __restrict__ Wq, const float* __restrict__ Wk,
    const float* __restrict__ Wv, const float* __restrict__ Wo,
    const float* __restrict__ W1, const float* __restrict__ W2,
    __bf16* __restrict__ WqkvT, __bf16* __restrict__ WoT,
    __bf16* __restrict__ W1T, __bf16* __restrict__ W2T) {
  __shared__ float tl[32][33];
  if (blockIdx.x < 4096) {                    // ---- prep part
    int i = blockIdx.x * 256 + threadIdx.x;   // float4 group
    float4 pv = ((const float4*)pos)[i];
    float4 qv = ((const float4*)q)[i];
    float4 kv = ((const float4*)k)[i];
    float4 vv = ((const float4*)v)[i];
    ushort4 o;
    o.x = bfb(qv.x + pv.x); o.y = bfb(qv.y + pv.y); o.z = bfb(qv.z + pv.z); o.w = bfb(qv.w + pv.w);
    ((ushort4*)xq)[i] = o;
    o.x = bfb(kv.x + pv.x); o.y = bfb(kv.y + pv.y); o.z = bfb(kv.z + pv.z); o.w = bfb(kv.w + pv.w);
    ((ushort4*)xk)[i] = o;
    o.x = bfb(vv.x); o.y = bfb(vv.y); o.z = bfb(vv.z); o.w = bfb(vv.w);
    ((ushort4*)xv)[i] = o;
    return;
  }
  int idx = blockIdx.x - 4096;                // ---- weight transpose part
  const float* src; __bf16* dst; int K, N, t;
  if (idx < 768) {
    src = idx < 256 ? Wq : (idx < 512 ? Wk : Wv);
    dst = WqkvT + (size_t)(idx >> 8) * 512 * 512;
    K = 512; N = 512; t = idx & 255;
  } else if (idx < 1024) { src = Wo; dst = WoT;  K = 512;  N = 512;  t = idx - 768; }
  else if (idx < 2048)   { src = W1; dst = W1T;  K = 512;  N = 2048; t = idx - 1024; }
  else                   { src = W2; dst = W2T;  K = 2048; N = 512;  t = idx - 2048; }
  int tiles_n = N >> 5;
  int tn = t & (tiles_n - 1), tk = t / tiles_n;
  int n0 = tn * 32, k0 = tk * 32;
  int x = threadIdx.x & 31, y4 = threadIdx.x >> 5;
  #pragma unroll
  for (int j = y4; j < 32; j += 8) tl[j][x] = src[(size_t)(k0 + j) * N + n0 + x];
  __syncthreads();
  #pragma unroll
  for (int j = y4; j < 32; j += 8)
    dst[(size_t)(n0 + j) * K + k0 + x] = (__bf16)tl[x][j];
}

// ---------------- GEMM: C[M,N] = A[M,K] @ BT[N,K]^T + bias ------------------
// 2-phase pipelined: double-buffered LDS, counted vmcnt, raw barriers.
// EPI: 0 bf16 store, 1 bf16 relu store, 2 f32 store, 3 bf16 store + V-section
//      written transposed to Vtp (QKV gemm only).
template <int EPI, int BN>
__global__ __launch_bounds__(256, 2) void gemm_bt(
    const __bf16* __restrict__ A0, const __bf16* __restrict__ A1, const __bf16* __restrict__ A2,
    const __bf16* __restrict__ BT,
    const float* __restrict__ bias0, const float* __restrict__ bias1, const float* __restrict__ bias2,
    void* __restrict__ Cp, __bf16* __restrict__ Vtp, int M, int N, int K, int nsplit) {
  constexpr int NFR = BN / 32;          // B frags per wave
  constexpr int WCW = BN / 2;           // wave col width
  constexpr int BI  = BN / 32;          // B staging instrs per thread
  __shared__ __align__(16) __bf16 As[2][128 * 64];
  __shared__ __align__(16) __bf16 Bs[2][BN * 64];
  int tid = threadIdx.x, lane = tid & 63;
  int wave = tid >> 6;
  int wr = (wave >> 1) * 64, wc = (wave & 1) * WCW;

  int gx = N / BN;
  int nwg = gridDim.x;
  int cpx = nwg >> 3;
  int swz = (blockIdx.x & 7) * cpx + (blockIdx.x >> 3);
  int bx = swz % gx, by = swz / gx;
  int row0 = by << 7, col0 = bx * BN;

  int asel = col0 / nsplit;
  const __bf16* A = asel == 0 ? A0 : (asel == 1 ? A1 : A2);
  const float* bias = asel == 0 ? bias0 : (asel == 1 ? bias1 : bias2);

  f32x4 acc[4][NFR] = {};

#define GSTAGE(BUF, KT)                                                        \
  { _Pragma("unroll")                                                          \
    for (int i = 0; i < 4; ++i) {                                              \
      int t = i * 256 + tid;                                                   \
      int r = t >> 3, cS = (t & 7) ^ (r & 7);                                  \
      gld_lds16(A + (size_t)(row0 + r) * K + (KT) + cS * 8, As[BUF] + t * 8);  \
    }                                                                          \
    _Pragma("unroll")                                                          \
    for (int i = 0; i < BI; ++i) {                                             \
      int t = i * 256 + tid;                                                   \
      int r = t >> 3, cS = (t & 7) ^ (r & 7);                                  \
      gld_lds16(BT + (size_t)(col0 + r) * K + (KT) + cS * 8, Bs[BUF] + t * 8); \
    } }

#define GCOMP(BUF)                                                             \
  { const __bf16* Asc = As[BUF];                                               \
    const __bf16* Bsc = Bs[BUF];                                               \
    _Pragma("unroll")                                                          \
    for (int ks = 0; ks < 2; ++ks) {                                           \
      bf16x8 af[4], bfr[NFR];                                                  \
      _Pragma("unroll")                                                        \
      for (int m = 0; m < 4; ++m) {                                            \
        int r = wr + m * 16 + (lane & 15);                                     \
        int c = (ks * 4 + (lane >> 4)) ^ (r & 7);                              \
        af[m] = *(const bf16x8*)(Asc + r * 64 + c * 8);                        \
      }                                                                        \
      _Pragma("unroll")                                                        \
      for (int n = 0; n < NFR; ++n) {                                          \
        int r = wc + n * 16 + (lane & 15);                                     \
        int c = (ks * 4 + (lane >> 4)) ^ (r & 7);                              \
        bfr[n] = *(const bf16x8*)(Bsc + r * 64 + c * 8);                       \
      }                                                                        \
      _Pragma("unroll")                                                        \
      for (int m = 0; m < 4; ++m)                                              \
        _Pragma("unroll")                                                      \
        for (int n = 0; n < NFR; ++n)                                          \
          acc[m][n] = __builtin_amdgcn_mfma_f32_16x16x32_bf16(af[m], bfr[n], acc[m][n], 0, 0, 0); \
    } }

  GSTAGE(0, 0)
  int cur = 0;
  for (int kt = 64; kt < K; kt += 64) {
    GSTAGE(cur ^ 1, kt)
    if constexpr (BN == 128) asm volatile("s_waitcnt vmcnt(8)" ::: "memory");
    else                     asm volatile("s_waitcnt vmcnt(6)" ::: "memory");
    __builtin_amdgcn_s_barrier();
    __builtin_amdgcn_sched_barrier(0);
    GCOMP(cur)
    __builtin_amdgcn_s_barrier();     // protect buf[cur] from next stage
    cur ^= 1;
  }
  asm volatile("s_waitcnt vmcnt(0)" ::: "memory");
  __builtin_amdgcn_s_barrier();
  __builtin_amdgcn_sched_barrier(0);
  GCOMP(cur)
#undef GSTAGE
#undef GCOMP

  // epilogue: C row = (lane>>4)*4 + j, col = lane&15  (m89-verified layout)
  int rb = row0 + wr + ((lane >> 4) << 2);
  int cb = col0 + wc + (lane & 15);
  if (EPI == 3 && asel == 2) {
    // V panel: write transposed into Vt[(b*8+h)*64+d][n], packed 4 rows (8B)
    int bb = row0 >> 10;
    #pragma unroll
    for (int n = 0; n < NFR; ++n) {
      int c = cb + n * 16;                    // global col in [1024,1536)
      int d = c & 63, hh = (c >> 6) & 7;
      float bv = bias[c % nsplit];
      size_t vbase = ((size_t)((bb * 8 + hh) * 64 + d)) << 10;
      #pragma unroll
      for (int m = 0; m < 4; ++m) {
        int r0 = (rb + m * 16) & 1023;
        ushort4 pk;
        pk.x = bfb(acc[m][n][0] + bv);
        pk.y = bfb(acc[m][n][1] + bv);
        pk.z = bfb(acc[m][n][2] + bv);
        pk.w = bfb(acc[m][n][3] + bv);
        *(ushort4*)((__bf16*)Vtp + vbase + r0) = pk;
      }
    }
    return;
  }
  #pragma unroll
  for (int n = 0; n < NFR; ++n) {
    int c = cb + n * 16;
    float bv = bias[c % nsplit];
    #pragma unroll
    for (int m = 0; m < 4; ++m) {
      #pragma unroll
      for (int j = 0; j < 4; ++j) {
        int r = rb + m * 16 + j;
        float v = acc[m][n][j] + bv;
        if (EPI == 1) v = fmaxf(v, 0.f);
        if (EPI == 2) ((float*)Cp)[(size_t)r * N + c] = v;
        else          ((__bf16*)Cp)[(size_t)r * N + c] = (__bf16)v;
      }
    }
  }
}

// ---------------- fused attention v6: 2 q-tiles per block --------------------
// softmax(log(clip(w)) + s) == normalize(clip(w) * exp(s)) exactly.
// SWAPPED QK^T: mfma(K,Q) -> lane owns q-row u, att-cols n*16+g*4+{0..3}.
// One block = 128 q-rows (2 tiles) sharing each staged K/V tile: grid 512 =
// EXACTLY 2 blocks/CU (no tail round), half the barrier convoys, 2x compute
// per phase. rgw: 2-deep x 2 tiles register prefetch issued mid-phase after
// consumption (queue at phase top = [KV:4, rgw:8] -> vmcnt(8) drains KV).
__global__ __launch_bounds__(256, 2) void attn_kernel(
    const __bf16* __restrict__ QKV, const __bf16* __restrict__ Vt,
    const float* __restrict__ rgw, __bf16* __restrict__ O) {
  __shared__ __align__(16) __bf16 Qs[128 * 64];
  __shared__ __align__(16) __bf16 Ks[2][64 * 64];
  __shared__ __align__(16) __bf16 Vs[2][64 * 64];
  __shared__ __align__(16) __bf16 Ps[4][16 * 64];

  int tid = threadIdx.x, lane = tid & 63, wave = tid >> 6;
  int flat = (blockIdx.x & 7) * 64 + (blockIdx.x >> 3);    // bijective XCD swz
  int qt = flat & 7, h = (flat >> 3) & 7, b = flat >> 6;
  int q0 = qt * 128;
  const int g = lane >> 4, u = lane & 15;

  const float* rgw_p0 = rgw +
      ((size_t)(b * H_ + h) * N_ + (size_t)(q0 + wave * 16 + u)) * N_ + g * 4;
  const float* rgw_p1 = rgw_p0 + (size_t)64 * N_;

#define STAGE_KV(BUF, KT)                                                      \
  {                                                                            \
    _Pragma("unroll")                                                          \
    for (int i = 0; i < 2; ++i) {                                              \
      int t = i * 256 + tid;                                                   \
      int r = t >> 3, cL = t & 7, cS = cL ^ (r & 7);                           \
      gld_lds16(QKV + (size_t)(b * N_ + (KT) + r) * QKV_LD + DM + h * 64 + cS * 8, Ks[BUF] + t * 8); \
      gld_lds16(Vt + (size_t)((b * H_ + h) * 64 + r) * N_ + (KT) + cS * 8, Vs[BUF] + t * 8);         \
    }                                                                          \
  }
#define RPF(W, P, T)                                                           \
  {                                                                            \
    _Pragma("unroll")                                                          \
    for (int n = 0; n < 4; ++n)                                                \
      W[n] = __builtin_nontemporal_load((const f32x4*)((P) + (size_t)(T) * 64 + n * 16)); \
  }

  // ---- prologue: Q (128 rows) + KV[0] -> LDS; rgw tiles 0,1 x 2 q-tiles ----
  #pragma unroll
  for (int i = 0; i < 4; ++i) {
    int t = i * 256 + tid;
    int r = t >> 3, cL = t & 7, cS = cL ^ (r & 7);
    gld_lds16(QKV + (size_t)(b * N_ + q0 + r) * QKV_LD + h * 64 + cS * 8, Qs + t * 8);
  }
  STAGE_KV(0, 0)
  __builtin_amdgcn_sched_barrier(0);
  f32x4 wA0[4], wA1[4], wB0[4], wB1[4];
  RPF(wA0, rgw_p0, 0) RPF(wA1, rgw_p1, 0)
  RPF(wB0, rgw_p0, 1) RPF(wB1, rgw_p1, 1)
  __builtin_amdgcn_sched_barrier(0);

  float l0 = 0.f, l1 = 0.f;
  f32x4 oacc0[4] = {}, oacc1[4] = {};
  bf16x8 qf0[2], qf1[2];
  __bf16* pw = &Ps[wave][0];

  union Pk { __bf16 h4[4]; unsigned long long q; };

#define TILE_ONE(T, CUR, QF, WC, RGWP, OA, LREF, DORPF)                        \
  {                                                                            \
    f32x4 s[4] = {};                                                           \
    __builtin_amdgcn_s_setprio(1);                                             \
    _Pragma("unroll")                                                          \
    for (int ks = 0; ks < 2; ++ks) {                                           \
      _Pragma("unroll")                                                        \
      for (int n = 0; n < 4; ++n) {                                            \
        int r = n * 16 + u;                                                    \
        int c = (ks * 4 + g) ^ (r & 7);                                        \
        bf16x8 kf = *(const bf16x8*)(Ks[CUR] + r * 64 + c * 8);                \
        s[n] = __builtin_amdgcn_mfma_f32_16x16x32_bf16(kf, QF[ks], s[n], 0, 0, 0); \
      }                                                                        \
    }                                                                          \
    __builtin_amdgcn_s_setprio(0);                                             \
    _Pragma("unroll")                                                          \
    for (int n = 0; n < 4; ++n) {                                              \
      Pk pk;                                                                   \
      _Pragma("unroll")                                                        \
      for (int j = 0; j < 4; ++j) {                                            \
        float pv = fmaxf(WC[n][j], 1e-6f) * exp2f(s[n][j] * SCL);              \
        LREF += pv;                                                            \
        pk.h4[j] = (__bf16)pv;                                                 \
      }                                                                        \
      int bcol = 2 * n + (g >> 1);                                             \
      *(unsigned long long*)(pw + u * 64 + ((bcol ^ (u & 7)) << 3) + ((g & 1) << 2)) = pk.q; \
    }                                                                          \
    __builtin_amdgcn_sched_barrier(0);                                         \
    if (DORPF) { RPF(WC, RGWP, (T) + 2) }                                      \
    __builtin_amdgcn_sched_barrier(0);                                         \
    __builtin_amdgcn_s_setprio(1);                                             \
    _Pragma("unroll")                                                          \
    for (int ks = 0; ks < 2; ++ks) {                                           \
      int cp = (ks * 4 + g) ^ (u & 7);                                         \
      bf16x8 pa = *(const bf16x8*)(pw + u * 64 + cp * 8);                      \
      _Pragma("unroll")                                                        \
      for (int n = 0; n < 4; ++n) {                                            \
        int r = n * 16 + u;                                                    \
        int c = (ks * 4 + g) ^ (r & 7);                                        \
        bf16x8 vb = *(const bf16x8*)(Vs[CUR] + r * 64 + c * 8);                \
        OA[n] = __builtin_amdgcn_mfma_f32_16x16x32_bf16(pa, vb, OA[n], 0, 0, 0); \
      }                                                                        \
    }                                                                          \
    __builtin_amdgcn_s_setprio(0);                                             \
  }

#define PHASE(T16, WAITSTR, DOSTAGE, DORPF, W0, W1)                            \
  {                                                                            \
    asm volatile(WAITSTR ::: "memory");                                        \
    __builtin_amdgcn_s_barrier();                                              \
    if (DOSTAGE) { STAGE_KV(((T16) + 1) & 1, ((T16) + 1) * 64) }               \
    __builtin_amdgcn_sched_barrier(0);                                         \
    if ((T16) == 0) {                                                          \
      int r = wave * 16 + u;                                                   \
      _Pragma("unroll")                                                        \
      for (int ks = 0; ks < 2; ++ks) {                                         \
        int c = (ks * 4 + g) ^ (r & 7);                                        \
        qf0[ks] = *(const bf16x8*)(Qs + r * 64 + c * 8);                       \
        qf1[ks] = *(const bf16x8*)(Qs + (64 + r) * 64 + c * 8);                \
      }                                                                        \
    }                                                                          \
    TILE_ONE(T16, (T16) & 1, qf0, W0, rgw_p0, oacc0, l0, DORPF)                \
    TILE_ONE(T16, (T16) & 1, qf1, W1, rgw_p1, oacc1, l1, DORPF)                \
  }

  PHASE(0,  "s_waitcnt vmcnt(16)", 1, 1, wA0, wA1)
  PHASE(1,  "s_waitcnt vmcnt(8)",  1, 1, wB0, wB1)
  PHASE(2,  "s_waitcnt vmcnt(8)",  1, 1, wA0, wA1)
  PHASE(3,  "s_waitcnt vmcnt(8)",  1, 1, wB0, wB1)
  PHASE(4,  "s_waitcnt vmcnt(8)",  1, 1, wA0, wA1)
  PHASE(5,  "s_waitcnt vmcnt(8)",  1, 1, wB0, wB1)
  PHASE(6,  "s_waitcnt vmcnt(8)",  1, 1, wA0, wA1)
  PHASE(7,  "s_waitcnt vmcnt(8)",  1, 1, wB0, wB1)
  PHASE(8,  "s_waitcnt vmcnt(8)",  1, 1, wA0, wA1)
  PHASE(9,  "s_waitcnt vmcnt(8)",  1, 1, wB0, wB1)
  PHASE(10, "s_waitcnt vmcnt(8)",  1, 1, wA0, wA1)
  PHASE(11, "s_waitcnt vmcnt(8)",  1, 1, wB0, wB1)
  PHASE(12, "s_waitcnt vmcnt(8)",  1, 1, wA0, wA1)
  PHASE(13, "s_waitcnt vmcnt(8)",  1, 1, wB0, wB1)
  PHASE(14, "s_waitcnt vmcnt(8)",  1, 0, wA0, wA1)
  PHASE(15, "s_waitcnt vmcnt(0)",  0, 0, wB0, wB1)
#undef PHASE
#undef TILE_ONE
#undef STAGE_KV
#undef RPF

  // row-sums: per lane (row u) partials; sum across the 4 g-groups
  l0 += __shfl_xor(l0, 16); l0 += __shfl_xor(l0, 32);
  l1 += __shfl_xor(l1, 16); l1 += __shfl_xor(l1, 32);
  float linv0[4], linv1[4];
  #pragma unroll
  for (int j = 0; j < 4; ++j) {
    int src = (lane & 48) | (g * 4 + j);
    linv0[j] = 1.f / __shfl(l0, src);
    linv1[j] = 1.f / __shfl(l1, src);
  }

  int orow = b * N_ + q0 + wave * 16 + g * 4;
  int ocol = h * 64 + u;
  #pragma unroll
  for (int j = 0; j < 4; ++j)
    #pragma unroll
    for (int n = 0; n < 4; ++n) {
      O[(size_t)(orow + j) * DM + ocol + n * 16] = (__bf16)(oacc0[n][j] * linv0[j]);
      O[(size_t)(orow + 64 + j) * DM + ocol + n * 16] = (__bf16)(oacc1[n][j] * linv1[j]);
    }
}

// ---------------- LayerNorm(x1 + x2); x2 optionally bf16 --------------------
template <int WRITE_BF, int X2BF>
__global__ __launch_bounds__(256) void ln_kernel(
    const float* __restrict__ x1, const void* __restrict__ x2v,
    const float* __restrict__ gw, const float* __restrict__ bw,
    float* __restrict__ outf, __bf16* __restrict__ outb) {
  __shared__ float red[8];
  int row = blockIdx.x, t = threadIdx.x;
  size_t base = (size_t)row * DM;
  float2 a = ((const float2*)(x1 + base))[t];
  float b0, b1;
  if (X2BF) {
    unsigned p = ((const unsigned*)x2v)[base / 2 + t];
    union { unsigned u; float f; } c0, c1;
    c0.u = p << 16; c1.u = p & 0xffff0000u;
    b0 = c0.f; b1 = c1.f;
  } else {
    float2 bb = ((const float2*)x2v)[base / 2 + t];
    b0 = bb.x; b1 = bb.y;
  }
  float v0 = a.x + b0, v1 = a.y + b1;
  float s = v0 + v1, s2 = v0 * v0 + v1 * v1;
  #pragma unroll
  for (int o = 32; o; o >>= 1) { s += __shfl_xor(s, o); s2 += __shfl_xor(s2, o); }
  int wave = t >> 6;
  if ((t & 63) == 0) { red[wave] = s; red[4 + wave] = s2; }
  __syncthreads();
  s = red[0] + red[1] + red[2] + red[3];
  s2 = red[4] + red[5] + red[6] + red[7];
  float mu = s * (1.f / DM);
  float var = s2 * (1.f / DM) - mu * mu;
  float rstd = rsqrtf(var + 1e-5f);
  float y0 = (v0 - mu) * rstd * gw[2 * t] + bw[2 * t];
  float y1 = (v1 - mu) * rstd * gw[2 * t + 1] + bw[2 * t + 1];
  float2 r; r.x = y0; r.y = y1;
  ((float2*)(outf + base))[t] = r;
  if (WRITE_BF) {
    ushort2 h; h.x = bfb(y0); h.y = bfb(y1);
    ((ushort2*)(outb + base))[t] = h;
  }
}

// ---------------- launch -----------------------------------------------------
extern "C" void kernel_launch(void* const* d_in, const int* in_sizes, int n_in,
                              void* d_out, int out_size, void* d_ws, size_t ws_size,
                              hipStream_t stream) {
  const float* queries = (const float*)d_in[0];
  const float* keys    = (const float*)d_in[1];
  const float* values  = (const float*)d_in[2];
  const float* rgw     = (const float*)d_in[3];
  const float* pos     = (const float*)d_in[4];
  const float* Wq = (const float*)d_in[5];
  const float* bq = (const float*)d_in[6];
  const float* Wk = (const float*)d_in[7];
  const float* bk = (const float*)d_in[8];
  const float* Wv = (const float*)d_in[9];
  const float* bv = (const float*)d_in[10];
  const float* Wo = (const float*)d_in[11];
  const float* bo = (const float*)d_in[12];
  const float* ln1g = (const float*)d_in[13];
  const float* ln1b = (const float*)d_in[14];
  const float* W1 = (const float*)d_in[15];
  const float* b1 = (const float*)d_in[16];
  const float* W2 = (const float*)d_in[17];
  const float* b2 = (const float*)d_in[18];
  const float* ln2g = (const float*)d_in[19];
  const float* ln2b = (const float*)d_in[20];
  float* out = (float*)d_out;

  char* ws = (char*)d_ws;
  const size_t SZX = (size_t)ROWS * DM * 2;        // 8 MB (bf16 8192x512)
  __bf16* Xq    = (__bf16*)(ws);
  __bf16* Xk    = (__bf16*)(ws + SZX);
  __bf16* Xv    = (__bf16*)(ws + 2 * SZX);
  __bf16* WqkvT = (__bf16*)(ws + 3 * SZX);                       // 1536x512
  __bf16* WoT   = (__bf16*)(ws + 3 * SZX + 1572864);             // 512x512
  __bf16* W1T   = (__bf16*)(ws + 3 * SZX + 2097152);             // 2048x512
  __bf16* W2T   = (__bf16*)(ws + 3 * SZX + 4194304);             // 512x2048
  __bf16* QKV   = (__bf16*)(ws + 3 * SZX + 6291456);             // 8192x1536
  __bf16* Vt    = (__bf16*)(ws + 3 * SZX + 6291456 + 3 * SZX);   // (B,H,64,N)
  __bf16* Oat   = (__bf16*)(ws + 3 * SZX + 6291456 + 4 * SZX);
  // aliases over dead regions:
  __bf16* attprojb = Xq;            // bf16 8192x512 over Xq (dead after QKV)
  __bf16* attoutb  = Xv;            // over Xv (dead after QKV GEMM)
  float*  attoutf  = (float*)QKV;   // f32 over QKV (dead after attention)
  __bf16* ff2b     = Vt;            // bf16 over Vt (dead after attention)
  __bf16* ff1      = (__bf16*)(ws + 3 * SZX + 6291456 + 5 * SZX); // 8192x2048

  prep_and_wt<<<4096 + 3072, 256, 0, stream>>>(
      queries, keys, values, pos, Xq, Xk, Xv,
      Wq, Wk, Wv, Wo, W1, W2, WqkvT, WoT, W1T, W2T);

  // QKV: C[8192,1536]; V panel goes straight to Vt (transposed)
  gemm_bt<3, 128><<<(ROWS / 128) * (QKV_LD / 128), 256, 0, stream>>>(
      Xq, Xk, Xv, WqkvT, bq, bk, bv, QKV, Vt, ROWS, QKV_LD, DM, DM);

  attn_kernel<<<B_ * H_ * (N_ / 128), 256, 0, stream>>>(QKV, Vt, rgw, Oat);

  // Wo -> bf16 attprojb; LN1(queries + attprojb) -> f32 + bf16
  gemm_bt<0, 64><<<(ROWS / 128) * (DM / 64), 256, 0, stream>>>(
      Oat, Oat, Oat, WoT, bo, bo, bo, attprojb, nullptr, ROWS, DM, DM, DM);

  ln_kernel<1, 1><<<ROWS, 256, 0, stream>>>(queries, attprojb, ln1g, ln1b, attoutf, attoutb);

  gemm_bt<1, 128><<<(ROWS / 128) * (DFF / 128), 256, 0, stream>>>(
      attoutb, attoutb, attoutb, W1T, b1, b1, b1, ff1, nullptr, ROWS, DFF, DM, DFF);

  // FF2 -> bf16 ff2b; LN2(attoutf + ff2b) -> out
  gemm_bt<0, 64><<<(ROWS / 128) * (DM / 64), 256, 0, stream>>>(
      ff1, ff1, ff1, W2T, b2, b2, b2, ff2b, nullptr, ROWS, DM, DFF, DM);

  ln_kernel<0, 1><<<ROWS, 256, 0, stream>>>(attoutf, ff2b, ln2g, ln2b, out, nullptr);
}